// Round 7
// baseline (2186.742 us; speedup 1.0000x reference)
//
#include <hip/hip_runtime.h>
#include <hip/hip_bf16.h>
#include <stdint.h>

#define NROWS 12288
#define DIM   512
#define KNBR  10

// gram_topk geometry
#define NC    8            // column chunks
#define CHUNK (NROWS / NC) // 1536
#define BM    128
#define BN    64
#define BK    32
#define CT    (CHUNK / BN) // 24 col-tiles per block
#define NSTEP (CT * 16)    // 384 linearized (ct,k) staging steps

typedef __attribute__((ext_vector_type(8))) short s16x8;
typedef __attribute__((ext_vector_type(4))) float f32x4;
typedef unsigned int u32;

// LDS byte offsets inside smem[]
#define OFF_A0    0        // A buf0: [4 kg][128 row][8 bf16] = 8192 B
#define OFF_A1    8192
#define OFF_B0    16384    // B buf0: [4 kg][64 row][8 bf16] = 4096 B
#define OFF_B1    20480
#define OFF_SLAB  24576    // [32][67] f32 = 8576 B
#define OFF_PARK  33152    // [128 rows][10] float2 = 10240 B
#define SMEM_SZ   43392

static __device__ __forceinline__ unsigned short f2bf(float x) {
  __hip_bfloat16 b = __float2bfloat16(x);
  return *reinterpret_cast<unsigned short*>(&b);
}

static __device__ __forceinline__ void gload16(const void* g, void* l) {
  __builtin_amdgcn_global_load_lds(
      (const __attribute__((address_space(1))) u32*)g,
      (__attribute__((address_space(3))) u32*)l, 16, 0, 0);
}

// Stable top-k insert: keeps list sorted by (value desc, index asc).
#define TOPK_INSERT(TV, TI, V, IDX)                                              \
  do {                                                                           \
    float _v = (V); int _i = (IDX);                                              \
    if (_v > TV[9] || (_v == TV[9] && _i < TI[9])) {                             \
      TV[9] = _v; TI[9] = _i;                                                    \
      _Pragma("unroll")                                                          \
      for (int _s = 9; _s > 0; --_s) {                                           \
        bool _sw = (TV[_s] > TV[_s-1]) ||                                        \
                   (TV[_s] == TV[_s-1] && TI[_s] < TI[_s-1]);                    \
        if (_sw) {                                                               \
          float _tf = TV[_s]; TV[_s] = TV[_s-1]; TV[_s-1] = _tf;                 \
          int   _ti = TI[_s]; TI[_s] = TI[_s-1]; TI[_s-1] = _ti;                 \
        }                                                                        \
      }                                                                          \
    }                                                                            \
  } while (0)

// ---------------- Kernel 1: norms + bf16 conversion ----------------
__global__ __launch_bounds__(256) void prep_kernel(
    const float* __restrict__ f, float* __restrict__ sq,
    unsigned short* __restrict__ fbf) {
  const int wid = threadIdx.x >> 6;
  const int lane = threadIdx.x & 63;
  const int row = blockIdx.x * 4 + wid;
  const float4* fr = (const float4*)(f + (size_t)row * DIM);
  ushort4* br = (ushort4*)(fbf + (size_t)row * DIM);
  float s = 0.f;
#pragma unroll
  for (int u = 0; u < 2; ++u) {
    float4 v = fr[u * 64 + lane];
    s += v.x * v.x + v.y * v.y + v.z * v.z + v.w * v.w;
    ushort4 h;
    h.x = f2bf(v.x); h.y = f2bf(v.y); h.z = f2bf(v.z); h.w = f2bf(v.w);
    br[u * 64 + lane] = h;
  }
#pragma unroll
  for (int off = 32; off; off >>= 1) s += __shfl_down(s, off);
  if (lane == 0) sq[row] = s;
}

// ---------------- Kernel 2: pipelined 128x64 MFMA gram + chunked top-10 -----
// grid (96, NC). Block (rt, ch): rows rt*128..+128 x chunk ch (1536 cols,
// 24 tiles of 64). 2-phase pipeline: stage(s+1) issued BEFORE compute(s),
// double-buffered LDS, one barrier per step -> load latency hides under
// ds_read+MFMA instead of serializing (round 6 was 100% serial: MfmaUtil 3.4%).
// Per-row top-10 lists live in LDS ("park") so the K-loop register live set
// stays ~90 VGPR (rounds 2-5: live set > granted budget -> GBs of scratch).
__global__ __launch_bounds__(256) void gram_topk(
    const unsigned short* __restrict__ fbf, const float* __restrict__ sq,
    float2* __restrict__ part, float* __restrict__ out) {
  __shared__ __align__(16) char smem[SMEM_SZ];
  __shared__ float sqr[BM];
  __shared__ float sqc[BN];

  const int t = threadIdx.x;
  const int lane = t & 63, wid = t >> 6;
  const int wr = wid >> 1, wc = wid & 1;     // wave -> 64-row half, 32-col half
  const int fr = lane & 15, kg = lane >> 4;  // MFMA fragment coords
  const int brow = blockIdx.x * BM;
  const int chunk = blockIdx.y;

  float* slab = (float*)(smem + OFF_SLAB);
  float2* park = (float2*)(smem + OFF_PARK);

  // Zero-fill this block's slice of the output (harness doesn't re-zero).
  {
    const int bid = blockIdx.y * 96 + blockIdx.x;          // 0..767
    const int per = NROWS * NROWS / (96 * NC) / 4;         // f32x4 per block
    f32x4* o4 = (f32x4*)out + (size_t)bid * per;
    f32x4 z = {0.f, 0.f, 0.f, 0.f};
    for (int i = t; i < per; i += 256) o4[i] = z;
  }
  if (t < BM) {
    sqr[t] = sq[brow + t];
#pragma unroll
    for (int s2 = 0; s2 < 10; ++s2)
      park[t * 10 + s2] = make_float2(-INFINITY, __int_as_float(0x7fffffff));
  }

  // stage step s = ct*16 + k: A kslice [4kg][128][8], B kslice [4kg][64][8]
  auto stage = [&](int s) {
    const int sct = s >> 4;
    const int kt = (s & 15) * BK;
    const int sbcol = chunk * CHUNK + sct * BN;
    char* ab = smem + ((s & 1) ? OFF_A1 : OFF_A0);
    char* bb = smem + ((s & 1) ? OFF_B1 : OFF_B0);
#pragma unroll
    for (int i = 0; i < 2; ++i) {
      const int c = i * 256 + t;
      gload16(&fbf[(size_t)(brow + (c & 127)) * DIM + kt + (c >> 7) * 8],
              ab + (i * 256 + wid * 64) * 16);
    }
    gload16(&fbf[(size_t)(sbcol + (t & 63)) * DIM + kt + (t >> 6) * 8],
            bb + (wid * 64) * 16);
  };

  stage(0);
  __syncthreads();   // drains vmcnt -> buf0 ready; also covers sqr/park init

  // scan ownership: thread t<128 owns tile row t (full 64-col scan per tile)
  const int mneed = (t & 63) >> 4;
  const int srow = ((t >> 6) << 4) + (t & 15);

  for (int ct = 0; ct < CT; ++ct) {
    const int bcol = chunk * CHUNK + ct * BN;

    f32x4 acc[4][2];
#pragma unroll
    for (int m = 0; m < 4; ++m)
#pragma unroll
      for (int n = 0; n < 2; ++n)
#pragma unroll
        for (int q = 0; q < 4; ++q) acc[m][n][q] = 0.f;

    for (int k = 0; k < 16; ++k) {
      const int s = ct * 16 + k;
      if (k == 0 && t < BN) sqc[t] = sq[bcol + t];  // read only in epilogue
      if (s + 1 < NSTEP) stage(s + 1);              // prefetch next k-slice

      const short* Abuf = (const short*)(smem + ((s & 1) ? OFF_A1 : OFF_A0));
      const short* Bbuf = (const short*)(smem + ((s & 1) ? OFF_B1 : OFF_B0));
      s16x8 a[4], b[2];
#pragma unroll
      for (int m = 0; m < 4; ++m)
        a[m] = *(const s16x8*)&Abuf[(kg * 128 + wr * 64 + m * 16 + fr) * 8];
#pragma unroll
      for (int n = 0; n < 2; ++n)
        b[n] = *(const s16x8*)&Bbuf[(kg * 64 + wc * 32 + n * 16 + fr) * 8];
#pragma unroll
      for (int m = 0; m < 4; ++m)
#pragma unroll
        for (int n = 0; n < 2; ++n)
          acc[m][n] = __builtin_amdgcn_mfma_f32_16x16x32_bf16(a[m], b[n], acc[m][n], 0, 0, 0);
      __syncthreads();  // end-of-read of buf(s) + drain of stage(s+1)
    }

    // epilogue: 4 phases of 32 rows x 64 cols; sim -> LDS slab -> stable scan.
    // (acc indices all compile-time constant: rule #20.)
#pragma unroll
    for (int m = 0; m < 4; ++m) {
#pragma unroll
      for (int n = 0; n < 2; ++n)
#pragma unroll
        for (int q = 0; q < 4; ++q) {
          const int rl = kg * 4 + q;            // 0..15 within band
          const int tr = wr * 64 + m * 16 + rl; // tile row
          const int tc = wc * 32 + n * 16 + fr; // tile col
          const float dist = sqr[tr] + sqc[tc] - 2.0f * acc[m][n][q];
          const float sv = ((brow + tr) == (bcol + tc)) ? 0.0f
                          : __expf(-fmaxf(dist, 0.0f));
          slab[(wr * 16 + rl) * 67 + tc] = sv;
        }
      __syncthreads();
      if (t < BM && mneed == m) {
        float mv[10]; int mi[10];
#pragma unroll
        for (int s2 = 0; s2 < 10; ++s2) {
          const float2 e = park[t * 10 + s2];
          mv[s2] = e.x; mi[s2] = __float_as_int(e.y);
        }
#pragma unroll
        for (int c = 0; c < 64; ++c) {
          const float v = slab[srow * 67 + c];
          TOPK_INSERT(mv, mi, v, bcol + c);
        }
#pragma unroll
        for (int s2 = 0; s2 < 10; ++s2)
          park[t * 10 + s2] = make_float2(mv[s2], __int_as_float(mi[s2]));
      }
      __syncthreads();
    }
  }

  // park[t] IS row (brow+t)'s chunk top-10: write to ws
  if (t < BM) {
    float2* dst = part + ((size_t)(brow + t) * NC + chunk) * 10;
#pragma unroll
    for (int s2 = 0; s2 < 10; ++s2) dst[s2] = park[t * 10 + s2];
  }
}

// ---------------- Kernel 3: merge NC chunk lists per row, scatter ones ------
__global__ __launch_bounds__(256) void merge_scatter(
    const float2* __restrict__ part, float* __restrict__ out) {
  const int t = threadIdx.x;
  if (t >= 128) return;
  const int r = blockIdx.x * 128 + t;
  float mv[10]; int mi[10];
#pragma unroll
  for (int s = 0; s < 10; ++s) { mv[s] = -INFINITY; mi[s] = 0x7fffffff; }
  const float2* p = part + (size_t)r * NC * 10;
#pragma unroll
  for (int c = 0; c < NC * 10; ++c)
    TOPK_INSERT(mv, mi, p[c].x, __float_as_int(p[c].y));
  float* orow = out + (size_t)r * NROWS;
#pragma unroll
  for (int s = 0; s < 10; ++s) orow[mi[s]] = 1.0f;
}

// ---------------- Fallback (round-1 single-kernel path, 12.6 MB ws) ---------
__global__ __launch_bounds__(256) void knn_fallback(
    const unsigned short* __restrict__ fbf, const float* __restrict__ sq,
    float* __restrict__ out) {
  __shared__ short aT[64][32];
  __shared__ short bT[64][32];
  __shared__ float simf[5120];
  __shared__ float sqrow[64];

  const int t = threadIdx.x;
  const int lane = t & 63, wid = t >> 6;
  const int wr = wid >> 1, wc = wid & 1;
  const int fr = lane & 15, kg = lane >> 4;
  const int brow = blockIdx.x * 64;

  {
    f32x4* o4 = (f32x4*)(out + (size_t)brow * NROWS);
    const int total4 = 64 * NROWS / 4;
    f32x4 z = {0.f, 0.f, 0.f, 0.f};
    for (int i = t; i < total4; i += 256) o4[i] = z;
  }
  if (t < 64) sqrow[t] = sq[brow + t];

  float tv[10]; int ti[10];
#pragma unroll
  for (int s = 0; s < 10; ++s) { tv[s] = -INFINITY; ti[s] = 0x7fffffff; }
  const int sstage_r = t >> 2;
  const int sstage_k = (t & 3) * 8;

  for (int ctile = 0; ctile < NROWS / 64; ++ctile) {
    const int bcol = ctile * 64;
    f32x4 acc[2][2];
#pragma unroll
    for (int m = 0; m < 2; ++m)
#pragma unroll
      for (int n = 0; n < 2; ++n)
#pragma unroll
        for (int q = 0; q < 4; ++q) acc[m][n][q] = 0.f;

    for (int kt = 0; kt < DIM; kt += 32) {
      *(s16x8*)&aT[sstage_r][sstage_k] =
          *(const s16x8*)&fbf[(size_t)(brow + sstage_r) * DIM + kt + sstage_k];
      *(s16x8*)&bT[sstage_r][sstage_k] =
          *(const s16x8*)&fbf[(size_t)(bcol + sstage_r) * DIM + kt + sstage_k];
      __syncthreads();
      s16x8 a0 = *(const s16x8*)&aT[wr * 32 + fr][kg * 8];
      s16x8 a1 = *(const s16x8*)&aT[wr * 32 + 16 + fr][kg * 8];
      s16x8 b0 = *(const s16x8*)&bT[wc * 32 + fr][kg * 8];
      s16x8 b1 = *(const s16x8*)&bT[wc * 32 + 16 + fr][kg * 8];
      acc[0][0] = __builtin_amdgcn_mfma_f32_16x16x32_bf16(a0, b0, acc[0][0], 0, 0, 0);
      acc[0][1] = __builtin_amdgcn_mfma_f32_16x16x32_bf16(a0, b1, acc[0][1], 0, 0, 0);
      acc[1][0] = __builtin_amdgcn_mfma_f32_16x16x32_bf16(a1, b0, acc[1][0], 0, 0, 0);
      acc[1][1] = __builtin_amdgcn_mfma_f32_16x16x32_bf16(a1, b1, acc[1][1], 0, 0, 0);
      __syncthreads();
    }
#pragma unroll
    for (int m = 0; m < 2; ++m)
#pragma unroll
      for (int n = 0; n < 2; ++n)
#pragma unroll
        for (int q = 0; q < 4; ++q) {
          int rl = wr * 32 + m * 16 + kg * 4 + q;
          int cl = wc * 32 + n * 16 + fr;
          float dist = sqrow[rl] + sq[bcol + cl] - 2.0f * acc[m][n][q];
          float sv = ((brow + rl) == (bcol + cl)) ? 0.0f : __expf(-fmaxf(dist, 0.0f));
          simf[rl * 65 + cl] = sv;
        }
    __syncthreads();
    {
      const int c0 = wid * 16;
#pragma unroll
      for (int c = 0; c < 16; ++c) {
        float v = simf[lane * 65 + c0 + c];
        TOPK_INSERT(tv, ti, v, bcol + c0 + c);
      }
    }
    __syncthreads();
  }
#pragma unroll
  for (int s = 0; s < 10; ++s) {
    simf[(lane * 4 + wid) * 20 + s * 2]     = tv[s];
    simf[(lane * 4 + wid) * 20 + s * 2 + 1] = __int_as_float(ti[s]);
  }
  __syncthreads();
  if (t < 64) {
    float mv[10]; int mi[10];
#pragma unroll
    for (int s = 0; s < 10; ++s) { mv[s] = -INFINITY; mi[s] = 0x7fffffff; }
#pragma unroll
    for (int p = 0; p < 4; ++p)
#pragma unroll
      for (int s = 0; s < 10; ++s) {
        float v = simf[(t * 4 + p) * 20 + s * 2];
        int idx = __float_as_int(simf[(t * 4 + p) * 20 + s * 2 + 1]);
        TOPK_INSERT(mv, mi, v, idx);
      }
    float* orow = out + (size_t)(brow + t) * NROWS;
#pragma unroll
    for (int s = 0; s < 10; ++s) orow[mi[s]] = 1.0f;
  }
}

extern "C" void kernel_launch(void* const* d_in, const int* in_sizes, int n_in,
                              void* d_out, int out_size, void* d_ws, size_t ws_size,
                              hipStream_t stream) {
  const float* f = (const float*)d_in[0];
  float* out = (float*)d_out;

  const size_t sq_bytes   = (size_t)NROWS * sizeof(float);          // 49152
  const size_t fbf_bytes  = (size_t)NROWS * DIM * sizeof(unsigned short);
  const size_t part_bytes = (size_t)NROWS * NC * 10 * sizeof(float2);

  float* sq = (float*)d_ws;
  unsigned short* fbf = (unsigned short*)((char*)d_ws + sq_bytes);
  float2* part = (float2*)((char*)d_ws + sq_bytes + fbf_bytes);

  if (ws_size >= sq_bytes + fbf_bytes + part_bytes) {
    prep_kernel<<<NROWS / 4, 256, 0, stream>>>(f, sq, fbf);
    gram_topk<<<dim3(NROWS / BM, NC), 256, 0, stream>>>(fbf, sq, part, out);
    merge_scatter<<<NROWS / 128, 256, 0, stream>>>(part, out);
  } else if (ws_size >= sq_bytes + fbf_bytes) {
    prep_kernel<<<NROWS / 4, 256, 0, stream>>>(f, sq, fbf);
    knn_fallback<<<NROWS / 64, 256, 0, stream>>>(fbf, sq, out);
  }
}

// Round 8
// 713.324 us; speedup vs baseline: 3.0656x; 3.0656x over previous
//
#include <hip/hip_runtime.h>
#include <hip/hip_bf16.h>
#include <stdint.h>

#define NROWS 12288
#define DIM   512
#define KNBR  10

#define NC    8            // column chunks
#define CHUNK (NROWS / NC) // 1536
#define BT    64           // tile (rows and cols)
#define CT    (CHUNK / BT) // 24 col-tiles per block
#define NRB   (NROWS / BT) // 192 row blocks

typedef __attribute__((ext_vector_type(8))) short s16x8;
typedef __attribute__((ext_vector_type(4))) float f32x4;

static __device__ __forceinline__ unsigned short f2bf(float x) {
  __hip_bfloat16 b = __float2bfloat16(x);
  return *reinterpret_cast<unsigned short*>(&b);
}

// Stable top-k insert: keeps list sorted by (value desc, index asc).
#define TOPK_INSERT(TV, TI, V, IDX)                                              \
  do {                                                                           \
    float _v = (V); int _i = (IDX);                                              \
    if (_v > TV[9] || (_v == TV[9] && _i < TI[9])) {                             \
      TV[9] = _v; TI[9] = _i;                                                    \
      _Pragma("unroll")                                                          \
      for (int _s = 9; _s > 0; --_s) {                                           \
        bool _sw = (TV[_s] > TV[_s-1]) ||                                        \
                   (TV[_s] == TV[_s-1] && TI[_s] < TI[_s-1]);                    \
        if (_sw) {                                                               \
          float _tf = TV[_s]; TV[_s] = TV[_s-1]; TV[_s-1] = _tf;                 \
          int   _ti = TI[_s]; TI[_s] = TI[_s-1]; TI[_s-1] = _ti;                 \
        }                                                                        \
      }                                                                          \
    }                                                                            \
  } while (0)

// ---------------- Kernel 1: norms + bf16 conversion ----------------
__global__ __launch_bounds__(256) void prep_kernel(
    const float* __restrict__ f, float* __restrict__ sq,
    unsigned short* __restrict__ fbf) {
  const int wid = threadIdx.x >> 6;
  const int lane = threadIdx.x & 63;
  const int row = blockIdx.x * 4 + wid;
  const float4* fr = (const float4*)(f + (size_t)row * DIM);
  ushort4* br = (ushort4*)(fbf + (size_t)row * DIM);
  float s = 0.f;
#pragma unroll
  for (int u = 0; u < 2; ++u) {
    float4 v = fr[u * 64 + lane];
    s += v.x * v.x + v.y * v.y + v.z * v.z + v.w * v.w;
    ushort4 h;
    h.x = f2bf(v.x); h.y = f2bf(v.y); h.z = f2bf(v.z); h.w = f2bf(v.w);
    br[u * 64 + lane] = h;
  }
#pragma unroll
  for (int off = 32; off; off >>= 1) s += __shfl_down(s, off);
  if (lane == 0) sq[row] = s;
}

// ---------------- Kernel 2: round-1 64x64 block, column-chunked -------------
// grid (192, 8). Block (rt, ch): rows rt*64..+64 x cols ch*1536..+1536.
// EXACTLY the round-1 kernel body (1402 us with only 192 blocks / 0.75
// blocks-per-CU) -- the single change is 8x more blocks via column chunking,
// so each CU holds ~4 independent barrier domains whose stalls interleave.
// Rounds 6-7 showed this structure is barrier/latency-bound, not pipe-bound;
// parallelism is the cheapest latency-hiding lever (Guideline 1 / m114).
__global__ __launch_bounds__(256) void gram_topk(
    const unsigned short* __restrict__ fbf, const float* __restrict__ sq,
    float2* __restrict__ part, float* __restrict__ out) {
  __shared__ short aT[BT][32];
  __shared__ short bT[BT][32];
  __shared__ float simf[5120];   // sim tile [64][65] (4160) / merge buf [64*80]
  __shared__ float sqrow[BT];

  const int t = threadIdx.x;
  const int lane = t & 63, wid = t >> 6;
  const int wr = wid >> 1, wc = wid & 1;      // wave -> 32x32 quadrant
  const int fr = lane & 15, kg = lane >> 4;   // MFMA fragment coords
  const int brow = blockIdx.x * BT;
  const int chunk = blockIdx.y;

  // Zero-fill this block's 1/1536 slice of the output.
  {
    const int bid = blockIdx.y * NRB + blockIdx.x;         // 0..1535
    const int per = NROWS * NROWS / (NRB * NC) / 4;        // f32x4 per block
    f32x4* o4 = (f32x4*)out + (size_t)bid * per;
    f32x4 z = {0.f, 0.f, 0.f, 0.f};
    for (int i = t; i < per; i += 256) o4[i] = z;
  }
  if (t < BT) sqrow[t] = sq[brow + t];

  // Per-thread partial top-10: thread (lane=row, wid=column-sub-slice).
  float tv[10]; int ti[10];
#pragma unroll
  for (int s = 0; s < 10; ++s) { tv[s] = -INFINITY; ti[s] = 0x7fffffff; }

  const int sstage_r = t >> 2;             // staging: 4 threads/row
  const int sstage_k = (t & 3) * 8;        // 8 bf16 (16B) each

  for (int ct = 0; ct < CT; ++ct) {
    const int bcol = chunk * CHUNK + ct * BT;
    f32x4 acc[2][2];
#pragma unroll
    for (int m = 0; m < 2; ++m)
#pragma unroll
      for (int n = 0; n < 2; ++n)
#pragma unroll
        for (int q = 0; q < 4; ++q) acc[m][n][q] = 0.f;

    for (int kt = 0; kt < DIM; kt += 32) {
      // Stage A (rows) and B (cols) k-slices, [64][32] bf16 each.
      *(s16x8*)&aT[sstage_r][sstage_k] =
          *(const s16x8*)&fbf[(size_t)(brow + sstage_r) * DIM + kt + sstage_k];
      *(s16x8*)&bT[sstage_r][sstage_k] =
          *(const s16x8*)&fbf[(size_t)(bcol + sstage_r) * DIM + kt + sstage_k];
      __syncthreads();
      s16x8 a0 = *(const s16x8*)&aT[wr * 32 + fr][kg * 8];
      s16x8 a1 = *(const s16x8*)&aT[wr * 32 + 16 + fr][kg * 8];
      s16x8 b0 = *(const s16x8*)&bT[wc * 32 + fr][kg * 8];
      s16x8 b1 = *(const s16x8*)&bT[wc * 32 + 16 + fr][kg * 8];
      acc[0][0] = __builtin_amdgcn_mfma_f32_16x16x32_bf16(a0, b0, acc[0][0], 0, 0, 0);
      acc[0][1] = __builtin_amdgcn_mfma_f32_16x16x32_bf16(a0, b1, acc[0][1], 0, 0, 0);
      acc[1][0] = __builtin_amdgcn_mfma_f32_16x16x32_bf16(a1, b0, acc[1][0], 0, 0, 0);
      acc[1][1] = __builtin_amdgcn_mfma_f32_16x16x32_bf16(a1, b1, acc[1][1], 0, 0, 0);
      __syncthreads();
    }

    // dist -> sim, write tile to LDS. C/D layout: col=lane&15, row=(lane>>4)*4+q.
#pragma unroll
    for (int m = 0; m < 2; ++m)
#pragma unroll
      for (int n = 0; n < 2; ++n)
#pragma unroll
        for (int q = 0; q < 4; ++q) {
          int rl = wr * 32 + m * 16 + kg * 4 + q;
          int cl = wc * 32 + n * 16 + fr;
          float dist = sqrow[rl] + sq[bcol + cl] - 2.0f * acc[m][n][q];
          float sv = ((brow + rl) == (bcol + cl)) ? 0.0f : __expf(-fmaxf(dist, 0.0f));
          simf[rl * 65 + cl] = sv;
        }
    __syncthreads();

    // Scan: wave `wid` scans its 16-col sub-slice of each of the 64 rows.
    {
      const int c0 = wid * 16;
#pragma unroll
      for (int c = 0; c < 16; ++c) {
        float v = simf[lane * 65 + c0 + c];
        TOPK_INSERT(tv, ti, v, bcol + c0 + c);
      }
    }
    __syncthreads();
  }

  // Dump 4 partial lists per row to LDS, then one thread per row merges and
  // writes the row's chunk top-10 to the workspace.
#pragma unroll
  for (int s = 0; s < 10; ++s) {
    simf[(lane * 4 + wid) * 20 + s * 2]     = tv[s];
    simf[(lane * 4 + wid) * 20 + s * 2 + 1] = __int_as_float(ti[s]);
  }
  __syncthreads();
  if (t < BT) {
    float mv[10]; int mi[10];
#pragma unroll
    for (int s = 0; s < 10; ++s) { mv[s] = -INFINITY; mi[s] = 0x7fffffff; }
#pragma unroll
    for (int p = 0; p < 4; ++p)
#pragma unroll
      for (int s = 0; s < 10; ++s) {
        float v = simf[(t * 4 + p) * 20 + s * 2];
        int idx = __float_as_int(simf[(t * 4 + p) * 20 + s * 2 + 1]);
        TOPK_INSERT(mv, mi, v, idx);
      }
    float2* dst = part + ((size_t)(brow + t) * NC + chunk) * 10;
#pragma unroll
    for (int s = 0; s < 10; ++s) dst[s] = make_float2(mv[s], __int_as_float(mi[s]));
  }
}

// ---------------- Kernel 3: merge NC chunk lists per row, scatter ones ------
__global__ __launch_bounds__(256) void merge_scatter(
    const float2* __restrict__ part, float* __restrict__ out) {
  const int t = threadIdx.x;
  if (t >= 128) return;
  const int r = blockIdx.x * 128 + t;
  float mv[10]; int mi[10];
#pragma unroll
  for (int s = 0; s < 10; ++s) { mv[s] = -INFINITY; mi[s] = 0x7fffffff; }
  const float2* p = part + (size_t)r * NC * 10;
#pragma unroll
  for (int c = 0; c < NC * 10; ++c)
    TOPK_INSERT(mv, mi, p[c].x, __float_as_int(p[c].y));
  float* orow = out + (size_t)r * NROWS;
#pragma unroll
  for (int s = 0; s < 10; ++s) orow[mi[s]] = 1.0f;
}

// ---------------- Fallback (round-1 single-kernel path, 12.6 MB ws) ---------
__global__ __launch_bounds__(256) void knn_fallback(
    const unsigned short* __restrict__ fbf, const float* __restrict__ sq,
    float* __restrict__ out) {
  __shared__ short aT[64][32];
  __shared__ short bT[64][32];
  __shared__ float simf[5120];
  __shared__ float sqrow[64];

  const int t = threadIdx.x;
  const int lane = t & 63, wid = t >> 6;
  const int wr = wid >> 1, wc = wid & 1;
  const int fr = lane & 15, kg = lane >> 4;
  const int brow = blockIdx.x * 64;

  {
    f32x4* o4 = (f32x4*)(out + (size_t)brow * NROWS);
    const int total4 = 64 * NROWS / 4;
    f32x4 z = {0.f, 0.f, 0.f, 0.f};
    for (int i = t; i < total4; i += 256) o4[i] = z;
  }
  if (t < 64) sqrow[t] = sq[brow + t];

  float tv[10]; int ti[10];
#pragma unroll
  for (int s = 0; s < 10; ++s) { tv[s] = -INFINITY; ti[s] = 0x7fffffff; }
  const int sstage_r = t >> 2;
  const int sstage_k = (t & 3) * 8;

  for (int ctile = 0; ctile < NROWS / 64; ++ctile) {
    const int bcol = ctile * 64;
    f32x4 acc[2][2];
#pragma unroll
    for (int m = 0; m < 2; ++m)
#pragma unroll
      for (int n = 0; n < 2; ++n)
#pragma unroll
        for (int q = 0; q < 4; ++q) acc[m][n][q] = 0.f;

    for (int kt = 0; kt < DIM; kt += 32) {
      *(s16x8*)&aT[sstage_r][sstage_k] =
          *(const s16x8*)&fbf[(size_t)(brow + sstage_r) * DIM + kt + sstage_k];
      *(s16x8*)&bT[sstage_r][sstage_k] =
          *(const s16x8*)&fbf[(size_t)(bcol + sstage_r) * DIM + kt + sstage_k];
      __syncthreads();
      s16x8 a0 = *(const s16x8*)&aT[wr * 32 + fr][kg * 8];
      s16x8 a1 = *(const s16x8*)&aT[wr * 32 + 16 + fr][kg * 8];
      s16x8 b0 = *(const s16x8*)&bT[wc * 32 + fr][kg * 8];
      s16x8 b1 = *(const s16x8*)&bT[wc * 32 + 16 + fr][kg * 8];
      acc[0][0] = __builtin_amdgcn_mfma_f32_16x16x32_bf16(a0, b0, acc[0][0], 0, 0, 0);
      acc[0][1] = __builtin_amdgcn_mfma_f32_16x16x32_bf16(a0, b1, acc[0][1], 0, 0, 0);
      acc[1][0] = __builtin_amdgcn_mfma_f32_16x16x32_bf16(a1, b0, acc[1][0], 0, 0, 0);
      acc[1][1] = __builtin_amdgcn_mfma_f32_16x16x32_bf16(a1, b1, acc[1][1], 0, 0, 0);
      __syncthreads();
    }
#pragma unroll
    for (int m = 0; m < 2; ++m)
#pragma unroll
      for (int n = 0; n < 2; ++n)
#pragma unroll
        for (int q = 0; q < 4; ++q) {
          int rl = wr * 32 + m * 16 + kg * 4 + q;
          int cl = wc * 32 + n * 16 + fr;
          float dist = sqrow[rl] + sq[bcol + cl] - 2.0f * acc[m][n][q];
          float sv = ((brow + rl) == (bcol + cl)) ? 0.0f : __expf(-fmaxf(dist, 0.0f));
          simf[rl * 65 + cl] = sv;
        }
    __syncthreads();
    {
      const int c0 = wid * 16;
#pragma unroll
      for (int c = 0; c < 16; ++c) {
        float v = simf[lane * 65 + c0 + c];
        TOPK_INSERT(tv, ti, v, bcol + c0 + c);
      }
    }
    __syncthreads();
  }
#pragma unroll
  for (int s = 0; s < 10; ++s) {
    simf[(lane * 4 + wid) * 20 + s * 2]     = tv[s];
    simf[(lane * 4 + wid) * 20 + s * 2 + 1] = __int_as_float(ti[s]);
  }
  __syncthreads();
  if (t < 64) {
    float mv[10]; int mi[10];
#pragma unroll
    for (int s = 0; s < 10; ++s) { mv[s] = -INFINITY; mi[s] = 0x7fffffff; }
#pragma unroll
    for (int p = 0; p < 4; ++p)
#pragma unroll
      for (int s = 0; s < 10; ++s) {
        float v = simf[(t * 4 + p) * 20 + s * 2];
        int idx = __float_as_int(simf[(t * 4 + p) * 20 + s * 2 + 1]);
        TOPK_INSERT(mv, mi, v, idx);
      }
    float* orow = out + (size_t)(brow + t) * NROWS;
#pragma unroll
    for (int s = 0; s < 10; ++s) orow[mi[s]] = 1.0f;
  }
}

extern "C" void kernel_launch(void* const* d_in, const int* in_sizes, int n_in,
                              void* d_out, int out_size, void* d_ws, size_t ws_size,
                              hipStream_t stream) {
  const float* f = (const float*)d_in[0];
  float* out = (float*)d_out;

  const size_t sq_bytes   = (size_t)NROWS * sizeof(float);          // 49152
  const size_t fbf_bytes  = (size_t)NROWS * DIM * sizeof(unsigned short);
  const size_t part_bytes = (size_t)NROWS * NC * 10 * sizeof(float2);

  float* sq = (float*)d_ws;
  unsigned short* fbf = (unsigned short*)((char*)d_ws + sq_bytes);
  float2* part = (float2*)((char*)d_ws + sq_bytes + fbf_bytes);

  if (ws_size >= sq_bytes + fbf_bytes + part_bytes) {
    prep_kernel<<<NROWS / 4, 256, 0, stream>>>(f, sq, fbf);
    gram_topk<<<dim3(NRB, NC), 256, 0, stream>>>(fbf, sq, part, out);
    merge_scatter<<<NROWS / 128, 256, 0, stream>>>(part, out);
  } else if (ws_size >= sq_bytes + fbf_bytes) {
    prep_kernel<<<NROWS / 4, 256, 0, stream>>>(f, sq, fbf);
    knn_fallback<<<NROWS / 64, 256, 0, stream>>>(fbf, sq, out);
  }
}

// Round 9
// 685.568 us; speedup vs baseline: 3.1897x; 1.0405x over previous
//
#include <hip/hip_runtime.h>
#include <hip/hip_bf16.h>
#include <stdint.h>

#define NROWS 12288
#define DIM   512
#define KNBR  10

#define NC    8            // column chunks
#define CHUNK (NROWS / NC) // 1536
#define BT    64           // tile (rows and cols)
#define CT    (CHUNK / BT) // 24 col-tiles per block
#define NRB   (NROWS / BT) // 192 row blocks

typedef __attribute__((ext_vector_type(8))) short s16x8;
typedef __attribute__((ext_vector_type(4))) float f32x4;

static __device__ __forceinline__ unsigned short f2bf(float x) {
  __hip_bfloat16 b = __float2bfloat16(x);
  return *reinterpret_cast<unsigned short*>(&b);
}

// Stable top-k insert: keeps list sorted by (value desc, index asc).
#define TOPK_INSERT(TV, TI, V, IDX)                                              \
  do {                                                                           \
    float _v = (V); int _i = (IDX);                                              \
    if (_v > TV[9] || (_v == TV[9] && _i < TI[9])) {                             \
      TV[9] = _v; TI[9] = _i;                                                    \
      _Pragma("unroll")                                                          \
      for (int _s = 9; _s > 0; --_s) {                                           \
        bool _sw = (TV[_s] > TV[_s-1]) ||                                        \
                   (TV[_s] == TV[_s-1] && TI[_s] < TI[_s-1]);                    \
        if (_sw) {                                                               \
          float _tf = TV[_s]; TV[_s] = TV[_s-1]; TV[_s-1] = _tf;                 \
          int   _ti = TI[_s]; TI[_s] = TI[_s-1]; TI[_s-1] = _ti;                 \
        }                                                                        \
      }                                                                          \
    }                                                                            \
  } while (0)

// ---------------- Kernel 1: norms + bf16 conversion ----------------
__global__ __launch_bounds__(256) void prep_kernel(
    const float* __restrict__ f, float* __restrict__ sq,
    unsigned short* __restrict__ fbf) {
  const int wid = threadIdx.x >> 6;
  const int lane = threadIdx.x & 63;
  const int row = blockIdx.x * 4 + wid;
  const float4* fr = (const float4*)(f + (size_t)row * DIM);
  ushort4* br = (ushort4*)(fbf + (size_t)row * DIM);
  float s = 0.f;
#pragma unroll
  for (int u = 0; u < 2; ++u) {
    float4 v = fr[u * 64 + lane];
    s += v.x * v.x + v.y * v.y + v.z * v.z + v.w * v.w;
    ushort4 h;
    h.x = f2bf(v.x); h.y = f2bf(v.y); h.z = f2bf(v.z); h.w = f2bf(v.w);
    br[u * 64 + lane] = h;
  }
#pragma unroll
  for (int off = 32; off; off >>= 1) s += __shfl_down(s, off);
  if (lane == 0) sq[row] = s;
}

// ---------------- Kernel 2: 64x64 tiles, column-chunked, LDS-swizzled -------
// grid (192, 8). Round-8 structure (713 us) + T2 XOR swizzle on the A/B tile
// 16B-slot index: byte ^= ((row&6)<<3). Round 8's [64][32] row-major tiles
// had 8-way bank conflicts on BOTH the staging ds_write_b128 and the fragment
// ds_read_b128 (SQ_LDS_BANK_CONFLICT=4.4e7, ~3x on ~14.5 GB of LDS traffic =
// the dominant cost). Swizzle verified by enumeration: each kg quarter-wave's
// reads cover all 8 four-bank slots across rows 0-7 (2-way residual = free);
// writes remain bijective/uniform. Sim tile stride 65->66 floats (65 = 1 mod
// 32 made 4-way write conflicts; 66 = 2 mod 32 -> 2-way = free).
__global__ __launch_bounds__(256) void gram_topk(
    const unsigned short* __restrict__ fbf, const float* __restrict__ sq,
    float2* __restrict__ part, float* __restrict__ out) {
  __shared__ short aT[BT * 32];
  __shared__ short bT[BT * 32];
  __shared__ float simf[5120];   // sim tile [64][66] (4224) / merge buf [64*80]
  __shared__ float sqrow[BT];

  const int t = threadIdx.x;
  const int lane = t & 63, wid = t >> 6;
  const int wr = wid >> 1, wc = wid & 1;      // wave -> 32x32 quadrant
  const int fr = lane & 15, kg = lane >> 4;   // MFMA fragment coords
  const int brow = blockIdx.x * BT;
  const int chunk = blockIdx.y;

  // Zero-fill this block's 1/1536 slice of the output.
  {
    const int bid = blockIdx.y * NRB + blockIdx.x;         // 0..1535
    const int per = NROWS * NROWS / (NRB * NC) / 4;        // f32x4 per block
    f32x4* o4 = (f32x4*)out + (size_t)bid * per;
    f32x4 z = {0.f, 0.f, 0.f, 0.f};
    for (int i = t; i < per; i += 256) o4[i] = z;
  }
  if (t < BT) sqrow[t] = sq[brow + t];

  // Per-thread partial top-10: thread (lane=row, wid=column-sub-slice).
  float tv[10]; int ti[10];
#pragma unroll
  for (int s = 0; s < 10; ++s) { tv[s] = -INFINITY; ti[s] = 0x7fffffff; }

  // staging: 4 threads/row, 16B each; swizzled slot within the 64B row
  const int sstage_r = t >> 2;
  const int sstage_g = (t & 3) * 8;                         // global k-offset (bf16)
  const int sstage_b = ((t & 3) * 16) ^ ((sstage_r & 6) << 3);  // LDS byte in row
  // fragment read swizzle: row&6 == fr&6 for rows wr*32+fr and wr*32+16+fr
  const int frx = (fr & 6) << 3;
  const int abyte = ((kg * 16) ^ frx);

  for (int ct = 0; ct < CT; ++ct) {
    const int bcol = chunk * CHUNK + ct * BT;
    f32x4 acc[2][2];
#pragma unroll
    for (int m = 0; m < 2; ++m)
#pragma unroll
      for (int n = 0; n < 2; ++n)
#pragma unroll
        for (int q = 0; q < 4; ++q) acc[m][n][q] = 0.f;

    for (int kt = 0; kt < DIM; kt += 32) {
      // Stage A (rows) and B (cols) k-slices, [64 rows][64 B] swizzled.
      *(s16x8*)((char*)aT + sstage_r * 64 + sstage_b) =
          *(const s16x8*)&fbf[(size_t)(brow + sstage_r) * DIM + kt + sstage_g];
      *(s16x8*)((char*)bT + sstage_r * 64 + sstage_b) =
          *(const s16x8*)&fbf[(size_t)(bcol + sstage_r) * DIM + kt + sstage_g];
      __syncthreads();
      s16x8 a0 = *(const s16x8*)((const char*)aT + (wr * 32 + fr) * 64 + abyte);
      s16x8 a1 = *(const s16x8*)((const char*)aT + (wr * 32 + 16 + fr) * 64 + abyte);
      s16x8 b0 = *(const s16x8*)((const char*)bT + (wc * 32 + fr) * 64 + abyte);
      s16x8 b1 = *(const s16x8*)((const char*)bT + (wc * 32 + 16 + fr) * 64 + abyte);
      acc[0][0] = __builtin_amdgcn_mfma_f32_16x16x32_bf16(a0, b0, acc[0][0], 0, 0, 0);
      acc[0][1] = __builtin_amdgcn_mfma_f32_16x16x32_bf16(a0, b1, acc[0][1], 0, 0, 0);
      acc[1][0] = __builtin_amdgcn_mfma_f32_16x16x32_bf16(a1, b0, acc[1][0], 0, 0, 0);
      acc[1][1] = __builtin_amdgcn_mfma_f32_16x16x32_bf16(a1, b1, acc[1][1], 0, 0, 0);
      __syncthreads();
    }

    // dist -> sim, write tile to LDS. C/D layout: col=lane&15, row=(lane>>4)*4+q.
#pragma unroll
    for (int m = 0; m < 2; ++m)
#pragma unroll
      for (int n = 0; n < 2; ++n)
#pragma unroll
        for (int q = 0; q < 4; ++q) {
          int rl = wr * 32 + m * 16 + kg * 4 + q;
          int cl = wc * 32 + n * 16 + fr;
          float dist = sqrow[rl] + sq[bcol + cl] - 2.0f * acc[m][n][q];
          float sv = ((brow + rl) == (bcol + cl)) ? 0.0f : __expf(-fmaxf(dist, 0.0f));
          simf[rl * 66 + cl] = sv;
        }
    __syncthreads();

    // Scan: wave `wid` scans its 16-col sub-slice of each of the 64 rows.
    {
      const int c0 = wid * 16;
#pragma unroll
      for (int c = 0; c < 16; ++c) {
        float v = simf[lane * 66 + c0 + c];
        TOPK_INSERT(tv, ti, v, bcol + c0 + c);
      }
    }
    __syncthreads();
  }

  // Dump 4 partial lists per row to LDS, then one thread per row merges and
  // writes the row's chunk top-10 to the workspace.
#pragma unroll
  for (int s = 0; s < 10; ++s) {
    simf[(lane * 4 + wid) * 20 + s * 2]     = tv[s];
    simf[(lane * 4 + wid) * 20 + s * 2 + 1] = __int_as_float(ti[s]);
  }
  __syncthreads();
  if (t < BT) {
    float mv[10]; int mi[10];
#pragma unroll
    for (int s = 0; s < 10; ++s) { mv[s] = -INFINITY; mi[s] = 0x7fffffff; }
#pragma unroll
    for (int p = 0; p < 4; ++p)
#pragma unroll
      for (int s = 0; s < 10; ++s) {
        float v = simf[(t * 4 + p) * 20 + s * 2];
        int idx = __float_as_int(simf[(t * 4 + p) * 20 + s * 2 + 1]);
        TOPK_INSERT(mv, mi, v, idx);
      }
    float2* dst = part + ((size_t)(brow + t) * NC + chunk) * 10;
#pragma unroll
    for (int s = 0; s < 10; ++s) dst[s] = make_float2(mv[s], __int_as_float(mi[s]));
  }
}

// ---------------- Kernel 3: merge NC chunk lists per row, scatter ones ------
__global__ __launch_bounds__(256) void merge_scatter(
    const float2* __restrict__ part, float* __restrict__ out) {
  const int t = threadIdx.x;
  if (t >= 128) return;
  const int r = blockIdx.x * 128 + t;
  float mv[10]; int mi[10];
#pragma unroll
  for (int s = 0; s < 10; ++s) { mv[s] = -INFINITY; mi[s] = 0x7fffffff; }
  const float2* p = part + (size_t)r * NC * 10;
#pragma unroll
  for (int c = 0; c < NC * 10; ++c)
    TOPK_INSERT(mv, mi, p[c].x, __float_as_int(p[c].y));
  float* orow = out + (size_t)r * NROWS;
#pragma unroll
  for (int s = 0; s < 10; ++s) orow[mi[s]] = 1.0f;
}

// ---------------- Fallback (round-1 single-kernel path, 12.6 MB ws) ---------
__global__ __launch_bounds__(256) void knn_fallback(
    const unsigned short* __restrict__ fbf, const float* __restrict__ sq,
    float* __restrict__ out) {
  __shared__ short aT[64][32];
  __shared__ short bT[64][32];
  __shared__ float simf[5120];
  __shared__ float sqrow[64];

  const int t = threadIdx.x;
  const int lane = t & 63, wid = t >> 6;
  const int wr = wid >> 1, wc = wid & 1;
  const int fr = lane & 15, kg = lane >> 4;
  const int brow = blockIdx.x * 64;

  {
    f32x4* o4 = (f32x4*)(out + (size_t)brow * NROWS);
    const int total4 = 64 * NROWS / 4;
    f32x4 z = {0.f, 0.f, 0.f, 0.f};
    for (int i = t; i < total4; i += 256) o4[i] = z;
  }
  if (t < 64) sqrow[t] = sq[brow + t];

  float tv[10]; int ti[10];
#pragma unroll
  for (int s = 0; s < 10; ++s) { tv[s] = -INFINITY; ti[s] = 0x7fffffff; }
  const int sstage_r = t >> 2;
  const int sstage_k = (t & 3) * 8;

  for (int ctile = 0; ctile < NROWS / 64; ++ctile) {
    const int bcol = ctile * 64;
    f32x4 acc[2][2];
#pragma unroll
    for (int m = 0; m < 2; ++m)
#pragma unroll
      for (int n = 0; n < 2; ++n)
#pragma unroll
        for (int q = 0; q < 4; ++q) acc[m][n][q] = 0.f;

    for (int kt = 0; kt < DIM; kt += 32) {
      *(s16x8*)&aT[sstage_r][sstage_k] =
          *(const s16x8*)&fbf[(size_t)(brow + sstage_r) * DIM + kt + sstage_k];
      *(s16x8*)&bT[sstage_r][sstage_k] =
          *(const s16x8*)&fbf[(size_t)(bcol + sstage_r) * DIM + kt + sstage_k];
      __syncthreads();
      s16x8 a0 = *(const s16x8*)&aT[wr * 32 + fr][kg * 8];
      s16x8 a1 = *(const s16x8*)&aT[wr * 32 + 16 + fr][kg * 8];
      s16x8 b0 = *(const s16x8*)&bT[wc * 32 + fr][kg * 8];
      s16x8 b1 = *(const s16x8*)&bT[wc * 32 + 16 + fr][kg * 8];
      acc[0][0] = __builtin_amdgcn_mfma_f32_16x16x32_bf16(a0, b0, acc[0][0], 0, 0, 0);
      acc[0][1] = __builtin_amdgcn_mfma_f32_16x16x32_bf16(a0, b1, acc[0][1], 0, 0, 0);
      acc[1][0] = __builtin_amdgcn_mfma_f32_16x16x32_bf16(a1, b0, acc[1][0], 0, 0, 0);
      acc[1][1] = __builtin_amdgcn_mfma_f32_16x16x32_bf16(a1, b1, acc[1][1], 0, 0, 0);
      __syncthreads();
    }
#pragma unroll
    for (int m = 0; m < 2; ++m)
#pragma unroll
      for (int n = 0; n < 2; ++n)
#pragma unroll
        for (int q = 0; q < 4; ++q) {
          int rl = wr * 32 + m * 16 + kg * 4 + q;
          int cl = wc * 32 + n * 16 + fr;
          float dist = sqrow[rl] + sq[bcol + cl] - 2.0f * acc[m][n][q];
          float sv = ((brow + rl) == (bcol + cl)) ? 0.0f : __expf(-fmaxf(dist, 0.0f));
          simf[rl * 65 + cl] = sv;
        }
    __syncthreads();
    {
      const int c0 = wid * 16;
#pragma unroll
      for (int c = 0; c < 16; ++c) {
        float v = simf[lane * 65 + c0 + c];
        TOPK_INSERT(tv, ti, v, bcol + c0 + c);
      }
    }
    __syncthreads();
  }
#pragma unroll
  for (int s = 0; s < 10; ++s) {
    simf[(lane * 4 + wid) * 20 + s * 2]     = tv[s];
    simf[(lane * 4 + wid) * 20 + s * 2 + 1] = __int_as_float(ti[s]);
  }
  __syncthreads();
  if (t < 64) {
    float mv[10]; int mi[10];
#pragma unroll
    for (int s = 0; s < 10; ++s) { mv[s] = -INFINITY; mi[s] = 0x7fffffff; }
#pragma unroll
    for (int p = 0; p < 4; ++p)
#pragma unroll
      for (int s = 0; s < 10; ++s) {
        float v = simf[(t * 4 + p) * 20 + s * 2];
        int idx = __float_as_int(simf[(t * 4 + p) * 20 + s * 2 + 1]);
        TOPK_INSERT(mv, mi, v, idx);
      }
    float* orow = out + (size_t)(brow + t) * NROWS;
#pragma unroll
    for (int s = 0; s < 10; ++s) orow[mi[s]] = 1.0f;
  }
}

extern "C" void kernel_launch(void* const* d_in, const int* in_sizes, int n_in,
                              void* d_out, int out_size, void* d_ws, size_t ws_size,
                              hipStream_t stream) {
  const float* f = (const float*)d_in[0];
  float* out = (float*)d_out;

  const size_t sq_bytes   = (size_t)NROWS * sizeof(float);          // 49152
  const size_t fbf_bytes  = (size_t)NROWS * DIM * sizeof(unsigned short);
  const size_t part_bytes = (size_t)NROWS * NC * 10 * sizeof(float2);

  float* sq = (float*)d_ws;
  unsigned short* fbf = (unsigned short*)((char*)d_ws + sq_bytes);
  float2* part = (float2*)((char*)d_ws + sq_bytes + fbf_bytes);

  if (ws_size >= sq_bytes + fbf_bytes + part_bytes) {
    prep_kernel<<<NROWS / 4, 256, 0, stream>>>(f, sq, fbf);
    gram_topk<<<dim3(NRB, NC), 256, 0, stream>>>(fbf, sq, part, out);
    merge_scatter<<<NROWS / 128, 256, 0, stream>>>(part, out);
  } else if (ws_size >= sq_bytes + fbf_bytes) {
    prep_kernel<<<NROWS / 4, 256, 0, stream>>>(f, sq, fbf);
    knn_fallback<<<NROWS / 64, 256, 0, stream>>>(fbf, sq, out);
  }
}

// Round 10
// 639.647 us; speedup vs baseline: 3.4187x; 1.0718x over previous
//
#include <hip/hip_runtime.h>
#include <hip/hip_bf16.h>
#include <stdint.h>

#define NROWS 12288
#define DIM   512
#define KNBR  10

#define NC    8            // column chunks
#define CHUNK (NROWS / NC) // 1536
#define BT    64           // tile (rows and cols)
#define CT    (CHUNK / BT) // 24 col-tiles per block
#define NRB   (NROWS / BT) // 192 row blocks
#define BK2   64           // K-slice per barrier round
#define KST   (DIM / BK2)  // 8 k-steps

typedef __attribute__((ext_vector_type(8))) short s16x8;
typedef __attribute__((ext_vector_type(4))) float f32x4;
typedef unsigned int u32;

static __device__ __forceinline__ unsigned short f2bf(float x) {
  __hip_bfloat16 b = __float2bfloat16(x);
  return *reinterpret_cast<unsigned short*>(&b);
}

static __device__ __forceinline__ void gload16(const void* g, void* l) {
  __builtin_amdgcn_global_load_lds(
      (const __attribute__((address_space(1))) u32*)g,
      (__attribute__((address_space(3))) u32*)l, 16, 0, 0);
}

// Stable top-k insert: keeps list sorted by (value desc, index asc).
#define TOPK_INSERT(TV, TI, V, IDX)                                              \
  do {                                                                           \
    float _v = (V); int _i = (IDX);                                              \
    if (_v > TV[9] || (_v == TV[9] && _i < TI[9])) {                             \
      TV[9] = _v; TI[9] = _i;                                                    \
      _Pragma("unroll")                                                          \
      for (int _s = 9; _s > 0; --_s) {                                           \
        bool _sw = (TV[_s] > TV[_s-1]) ||                                        \
                   (TV[_s] == TV[_s-1] && TI[_s] < TI[_s-1]);                    \
        if (_sw) {                                                               \
          float _tf = TV[_s]; TV[_s] = TV[_s-1]; TV[_s-1] = _tf;                 \
          int   _ti = TI[_s]; TI[_s] = TI[_s-1]; TI[_s-1] = _ti;                 \
        }                                                                        \
      }                                                                          \
    }                                                                            \
  } while (0)

// ---------------- Kernel 1: norms + bf16 conversion ----------------
__global__ __launch_bounds__(256) void prep_kernel(
    const float* __restrict__ f, float* __restrict__ sq,
    unsigned short* __restrict__ fbf) {
  const int wid = threadIdx.x >> 6;
  const int lane = threadIdx.x & 63;
  const int row = blockIdx.x * 4 + wid;
  const float4* fr = (const float4*)(f + (size_t)row * DIM);
  ushort4* br = (ushort4*)(fbf + (size_t)row * DIM);
  float s = 0.f;
#pragma unroll
  for (int u = 0; u < 2; ++u) {
    float4 v = fr[u * 64 + lane];
    s += v.x * v.x + v.y * v.y + v.z * v.z + v.w * v.w;
    ushort4 h;
    h.x = f2bf(v.x); h.y = f2bf(v.y); h.z = f2bf(v.z); h.w = f2bf(v.w);
    br[u * 64 + lane] = h;
  }
#pragma unroll
  for (int off = 32; off; off >>= 1) s += __shfl_down(s, off);
  if (lane == 0) sq[row] = s;
}

// ---------------- Kernel 2: 64x64 tiles, BK=64, gload_lds, double-buffered --
// grid (192, 8). Round-9 structure + three changes (theory: barrier-bound):
//  1. BK 32->64: 8 MFMA per wave per barrier-pair (was 4); 9 barriers/ct (was 17).
//  2. global_load_lds width-16 staging (no VGPR round-trip). LDS dest is
//     LINEAR (HW requirement, rule #21); the bank swizzle is applied to the
//     GLOBAL source address instead: chunk (row, slot) holds k-group
//     g = slot ^ (row&7); fragment reads use byte ((h*4+kg)^(fr&7))*16.
//     Coalescing intact: permutation stays inside each row's 128B segment.
//  3. Double-buffer + stage(k+1)-before-compute(k), ONE barrier per step:
//     the barrier's vmcnt(0) drains loads that had the whole ds_read+MFMA
//     phase in flight (T3-minimum). No cross-ct prefetch (keeps LDS overlays
//     legal); the one exposed load per ct is ~2% of block time.
// LDS 32.8KB + VGPR<=128 -> 4 blocks/CU co-resident (round 8's proven lever).
__global__ __launch_bounds__(256) void gram_topk(
    const unsigned short* __restrict__ fbf, const float* __restrict__ sq,
    float2* __restrict__ part, float* __restrict__ out) {
  // smem: staging buffers A0|A1|B0|B1 (4 x 8KB). simf [64][66] f32 (16896B)
  // and the merge dump (20480B) OVERLAY the buffers (dead at those points).
  __shared__ __align__(16) char smem[32768];
  __shared__ float sqrow[BT];
  float* simf = (float*)smem;

  const int t = threadIdx.x;
  const int lane = t & 63, wid = t >> 6;
  const int wr = wid >> 1, wc = wid & 1;      // wave -> 32x32 quadrant
  const int fr = lane & 15, kg = lane >> 4;   // MFMA fragment coords
  const int brow = blockIdx.x * BT;
  const int chunk = blockIdx.y;

  // Zero-fill this block's 1/1536 slice of the output.
  {
    const int bid = blockIdx.y * NRB + blockIdx.x;         // 0..1535
    const int per = NROWS * NROWS / (NRB * NC) / 4;        // f32x4 per block
    f32x4* o4 = (f32x4*)out + (size_t)bid * per;
    f32x4 z = {0.f, 0.f, 0.f, 0.f};
    for (int i = t; i < per; i += 256) o4[i] = z;
  }
  if (t < BT) sqrow[t] = sq[brow + t];

  float tv[10]; int ti[10];
#pragma unroll
  for (int s = 0; s < 10; ++s) { tv[s] = -INFINITY; ti[s] = 0x7fffffff; }

  // staging geometry: 512 chunks of 16B per matrix per k-step; thread t takes
  // chunks t and t+256. chunk c: row=c>>3, slot=c&7, src k-group = slot^(row&7).
  const int c0r = t >> 3;
  const int c1r = (t + 256) >> 3;
  const size_t g0 = (size_t)c0r * DIM + (((t & 7) ^ (c0r & 7)) * 8);
  const size_t g1 = (size_t)c1r * DIM + (((t & 7) ^ (c1r & 7)) * 8);
  const int d0 = wid * 1024;          // LDS dest base, wave-uniform (+lane*16 by HW)
  const int d1 = 4096 + wid * 1024;
  const unsigned short* arow = fbf + (size_t)brow * DIM;

  for (int ct = 0; ct < CT; ++ct) {
    const int bcol = chunk * CHUNK + ct * BT;
    const unsigned short* bcolp = fbf + (size_t)bcol * DIM;

    f32x4 acc[2][2];
#pragma unroll
    for (int m = 0; m < 2; ++m)
#pragma unroll
      for (int n = 0; n < 2; ++n)
#pragma unroll
        for (int q = 0; q < 4; ++q) acc[m][n][q] = 0.f;

    // stage(kt, buf): issue 4 global_load_lds (A x2, B x2)
#define STAGE(KT, BUF)                                                       \
    do {                                                                     \
      char* ab_ = smem + (BUF) * 8192;                                       \
      char* bb_ = smem + 16384 + (BUF) * 8192;                               \
      gload16(arow + (KT) + g0, ab_ + d0);                                   \
      gload16(arow + (KT) + g1, ab_ + d1);                                   \
      gload16(bcolp + (KT) + g0, bb_ + d0);                                  \
      gload16(bcolp + (KT) + g1, bb_ + d1);                                  \
    } while (0)

    STAGE(0, 0);
    __syncthreads();   // buf0 ready (vmcnt drained); also covers sqrow init

    for (int k = 0; k < KST; ++k) {
      if (k < KST - 1) STAGE((k + 1) * BK2, (k + 1) & 1);
      const char* ab = smem + (k & 1) * 8192;
      const char* bb = smem + 16384 + (k & 1) * 8192;
#pragma unroll
      for (int h = 0; h < 2; ++h) {
        const int ob = (((h << 2) | kg) ^ (fr & 7)) << 4;
        s16x8 a0 = *(const s16x8*)(ab + (wr * 32 + fr) * 128 + ob);
        s16x8 a1 = *(const s16x8*)(ab + (wr * 32 + 16 + fr) * 128 + ob);
        s16x8 b0 = *(const s16x8*)(bb + (wc * 32 + fr) * 128 + ob);
        s16x8 b1 = *(const s16x8*)(bb + (wc * 32 + 16 + fr) * 128 + ob);
        acc[0][0] = __builtin_amdgcn_mfma_f32_16x16x32_bf16(a0, b0, acc[0][0], 0, 0, 0);
        acc[0][1] = __builtin_amdgcn_mfma_f32_16x16x32_bf16(a0, b1, acc[0][1], 0, 0, 0);
        acc[1][0] = __builtin_amdgcn_mfma_f32_16x16x32_bf16(a1, b0, acc[1][0], 0, 0, 0);
        acc[1][1] = __builtin_amdgcn_mfma_f32_16x16x32_bf16(a1, b1, acc[1][1], 0, 0, 0);
      }
      __syncthreads();  // readers done with buf(k) + stage(k+1) drained
    }
#undef STAGE

    // epilogue: dist -> sim, write tile to LDS (overlays dead staging bufs).
    // C/D layout: col=lane&15, row=(lane>>4)*4+q. All acc indices static.
#pragma unroll
    for (int m = 0; m < 2; ++m)
#pragma unroll
      for (int n = 0; n < 2; ++n)
#pragma unroll
        for (int q = 0; q < 4; ++q) {
          int rl = wr * 32 + m * 16 + kg * 4 + q;
          int cl = wc * 32 + n * 16 + fr;
          float dist = sqrow[rl] + sq[bcol + cl] - 2.0f * acc[m][n][q];
          float sv = ((brow + rl) == (bcol + cl)) ? 0.0f : __expf(-fmaxf(dist, 0.0f));
          simf[rl * 66 + cl] = sv;
        }
    __syncthreads();

    // Scan: wave `wid` scans its 16-col sub-slice of each of the 64 rows.
    {
      const int c0 = wid * 16;
#pragma unroll
      for (int c = 0; c < 16; ++c) {
        float v = simf[lane * 66 + c0 + c];
        TOPK_INSERT(tv, ti, v, bcol + c0 + c);
      }
    }
    __syncthreads();   // scan done before buffers are re-staged next ct
  }

  // Dump 4 partial lists per row to LDS, then one thread per row merges and
  // writes the row's chunk top-10 to the workspace.
#pragma unroll
  for (int s = 0; s < 10; ++s) {
    simf[(lane * 4 + wid) * 20 + s * 2]     = tv[s];
    simf[(lane * 4 + wid) * 20 + s * 2 + 1] = __int_as_float(ti[s]);
  }
  __syncthreads();
  if (t < BT) {
    float mv[10]; int mi[10];
#pragma unroll
    for (int s = 0; s < 10; ++s) { mv[s] = -INFINITY; mi[s] = 0x7fffffff; }
#pragma unroll
    for (int p = 0; p < 4; ++p)
#pragma unroll
      for (int s = 0; s < 10; ++s) {
        float v = simf[(t * 4 + p) * 20 + s * 2];
        int idx = __float_as_int(simf[(t * 4 + p) * 20 + s * 2 + 1]);
        TOPK_INSERT(mv, mi, v, idx);
      }
    float2* dst = part + ((size_t)(brow + t) * NC + chunk) * 10;
#pragma unroll
    for (int s = 0; s < 10; ++s) dst[s] = make_float2(mv[s], __int_as_float(mi[s]));
  }
}

// ---------------- Kernel 3: merge NC chunk lists per row, scatter ones ------
__global__ __launch_bounds__(256) void merge_scatter(
    const float2* __restrict__ part, float* __restrict__ out) {
  const int t = threadIdx.x;
  if (t >= 128) return;
  const int r = blockIdx.x * 128 + t;
  float mv[10]; int mi[10];
#pragma unroll
  for (int s = 0; s < 10; ++s) { mv[s] = -INFINITY; mi[s] = 0x7fffffff; }
  const float2* p = part + (size_t)r * NC * 10;
#pragma unroll
  for (int c = 0; c < NC * 10; ++c)
    TOPK_INSERT(mv, mi, p[c].x, __float_as_int(p[c].y));
  float* orow = out + (size_t)r * NROWS;
#pragma unroll
  for (int s = 0; s < 10; ++s) orow[mi[s]] = 1.0f;
}

// ---------------- Fallback (round-1 single-kernel path, 12.6 MB ws) ---------
__global__ __launch_bounds__(256) void knn_fallback(
    const unsigned short* __restrict__ fbf, const float* __restrict__ sq,
    float* __restrict__ out) {
  __shared__ short aT[64][32];
  __shared__ short bT[64][32];
  __shared__ float simf[5120];
  __shared__ float sqrow[64];

  const int t = threadIdx.x;
  const int lane = t & 63, wid = t >> 6;
  const int wr = wid >> 1, wc = wid & 1;
  const int fr = lane & 15, kg = lane >> 4;
  const int brow = blockIdx.x * 64;

  {
    f32x4* o4 = (f32x4*)(out + (size_t)brow * NROWS);
    const int total4 = 64 * NROWS / 4;
    f32x4 z = {0.f, 0.f, 0.f, 0.f};
    for (int i = t; i < total4; i += 256) o4[i] = z;
  }
  if (t < 64) sqrow[t] = sq[brow + t];

  float tv[10]; int ti[10];
#pragma unroll
  for (int s = 0; s < 10; ++s) { tv[s] = -INFINITY; ti[s] = 0x7fffffff; }
  const int sstage_r = t >> 2;
  const int sstage_k = (t & 3) * 8;

  for (int ctile = 0; ctile < NROWS / 64; ++ctile) {
    const int bcol = ctile * 64;
    f32x4 acc[2][2];
#pragma unroll
    for (int m = 0; m < 2; ++m)
#pragma unroll
      for (int n = 0; n < 2; ++n)
#pragma unroll
        for (int q = 0; q < 4; ++q) acc[m][n][q] = 0.f;

    for (int kt = 0; kt < DIM; kt += 32) {
      *(s16x8*)&aT[sstage_r][sstage_k] =
          *(const s16x8*)&fbf[(size_t)(brow + sstage_r) * DIM + kt + sstage_k];
      *(s16x8*)&bT[sstage_r][sstage_k] =
          *(const s16x8*)&fbf[(size_t)(bcol + sstage_r) * DIM + kt + sstage_k];
      __syncthreads();
      s16x8 a0 = *(const s16x8*)&aT[wr * 32 + fr][kg * 8];
      s16x8 a1 = *(const s16x8*)&aT[wr * 32 + 16 + fr][kg * 8];
      s16x8 b0 = *(const s16x8*)&bT[wc * 32 + fr][kg * 8];
      s16x8 b1 = *(const s16x8*)&bT[wc * 32 + 16 + fr][kg * 8];
      acc[0][0] = __builtin_amdgcn_mfma_f32_16x16x32_bf16(a0, b0, acc[0][0], 0, 0, 0);
      acc[0][1] = __builtin_amdgcn_mfma_f32_16x16x32_bf16(a0, b1, acc[0][1], 0, 0, 0);
      acc[1][0] = __builtin_amdgcn_mfma_f32_16x16x32_bf16(a1, b0, acc[1][0], 0, 0, 0);
      acc[1][1] = __builtin_amdgcn_mfma_f32_16x16x32_bf16(a1, b1, acc[1][1], 0, 0, 0);
      __syncthreads();
    }
#pragma unroll
    for (int m = 0; m < 2; ++m)
#pragma unroll
      for (int n = 0; n < 2; ++n)
#pragma unroll
        for (int q = 0; q < 4; ++q) {
          int rl = wr * 32 + m * 16 + kg * 4 + q;
          int cl = wc * 32 + n * 16 + fr;
          float dist = sqrow[rl] + sq[bcol + cl] - 2.0f * acc[m][n][q];
          float sv = ((brow + rl) == (bcol + cl)) ? 0.0f : __expf(-fmaxf(dist, 0.0f));
          simf[rl * 65 + cl] = sv;
        }
    __syncthreads();
    {
      const int c0 = wid * 16;
#pragma unroll
      for (int c = 0; c < 16; ++c) {
        float v = simf[lane * 65 + c0 + c];
        TOPK_INSERT(tv, ti, v, bcol + c0 + c);
      }
    }
    __syncthreads();
  }
#pragma unroll
  for (int s = 0; s < 10; ++s) {
    simf[(lane * 4 + wid) * 20 + s * 2]     = tv[s];
    simf[(lane * 4 + wid) * 20 + s * 2 + 1] = __int_as_float(ti[s]);
  }
  __syncthreads();
  if (t < 64) {
    float mv[10]; int mi[10];
#pragma unroll
    for (int s = 0; s < 10; ++s) { mv[s] = -INFINITY; mi[s] = 0x7fffffff; }
#pragma unroll
    for (int p = 0; p < 4; ++p)
#pragma unroll
      for (int s = 0; s < 10; ++s) {
        float v = simf[(t * 4 + p) * 20 + s * 2];
        int idx = __float_as_int(simf[(t * 4 + p) * 20 + s * 2 + 1]);
        TOPK_INSERT(mv, mi, v, idx);
      }
    float* orow = out + (size_t)(brow + t) * NROWS;
#pragma unroll
    for (int s = 0; s < 10; ++s) orow[mi[s]] = 1.0f;
  }
}

extern "C" void kernel_launch(void* const* d_in, const int* in_sizes, int n_in,
                              void* d_out, int out_size, void* d_ws, size_t ws_size,
                              hipStream_t stream) {
  const float* f = (const float*)d_in[0];
  float* out = (float*)d_out;

  const size_t sq_bytes   = (size_t)NROWS * sizeof(float);          // 49152
  const size_t fbf_bytes  = (size_t)NROWS * DIM * sizeof(unsigned short);
  const size_t part_bytes = (size_t)NROWS * NC * 10 * sizeof(float2);

  float* sq = (float*)d_ws;
  unsigned short* fbf = (unsigned short*)((char*)d_ws + sq_bytes);
  float2* part = (float2*)((char*)d_ws + sq_bytes + fbf_bytes);

  if (ws_size >= sq_bytes + fbf_bytes + part_bytes) {
    prep_kernel<<<NROWS / 4, 256, 0, stream>>>(f, sq, fbf);
    gram_topk<<<dim3(NRB, NC), 256, 0, stream>>>(fbf, sq, part, out);
    merge_scatter<<<NROWS / 128, 256, 0, stream>>>(part, out);
  } else if (ws_size >= sq_bytes + fbf_bytes) {
    prep_kernel<<<NROWS / 4, 256, 0, stream>>>(f, sq, fbf);
    knn_fallback<<<NROWS / 64, 256, 0, stream>>>(fbf, sq, out);
  }
}

// Round 11
// 584.144 us; speedup vs baseline: 3.7435x; 1.0950x over previous
//
#include <hip/hip_runtime.h>
#include <hip/hip_bf16.h>
#include <stdint.h>

#define NROWS 12288
#define DIM   512
#define KNBR  10

#define NC    8            // column chunks
#define CHUNK (NROWS / NC) // 1536
#define BT    64           // tile (rows and cols)
#define CT    (CHUNK / BT) // 24 col-tiles per block
#define NRB   (NROWS / BT) // 192 row blocks
#define BK2   64           // K-slice per barrier round
#define KST   (DIM / BK2)  // 8 k-steps

// exp(-x) == +0.0f (round-nearest) for all x >= 104: exp(-104)=6.2e-46 <
// 2^-150 = half of FLT_MIN_SUBNORM. Conservative vs the true cutoff 103.28.
#define UNDERFLOW_DIST 104.0f

typedef __attribute__((ext_vector_type(8))) short s16x8;
typedef __attribute__((ext_vector_type(4))) float f32x4;
typedef unsigned int u32;

static __device__ __forceinline__ unsigned short f2bf(float x) {
  __hip_bfloat16 b = __float2bfloat16(x);
  return *reinterpret_cast<unsigned short*>(&b);
}

static __device__ __forceinline__ void gload16(const void* g, void* l) {
  __builtin_amdgcn_global_load_lds(
      (const __attribute__((address_space(1))) u32*)g,
      (__attribute__((address_space(3))) u32*)l, 16, 0, 0);
}

// Stable top-k insert: keeps list sorted by (value desc, index asc).
#define TOPK_INSERT(TV, TI, V, IDX)                                              \
  do {                                                                           \
    float _v = (V); int _i = (IDX);                                              \
    if (_v > TV[9] || (_v == TV[9] && _i < TI[9])) {                             \
      TV[9] = _v; TI[9] = _i;                                                    \
      _Pragma("unroll")                                                          \
      for (int _s = 9; _s > 0; --_s) {                                           \
        bool _sw = (TV[_s] > TV[_s-1]) ||                                        \
                   (TV[_s] == TV[_s-1] && TI[_s] < TI[_s-1]);                    \
        if (_sw) {                                                               \
          float _tf = TV[_s]; TV[_s] = TV[_s-1]; TV[_s-1] = _tf;                 \
          int   _ti = TI[_s]; TI[_s] = TI[_s-1]; TI[_s-1] = _ti;                 \
        }                                                                        \
      }                                                                          \
    }                                                                            \
  } while (0)

// ---------------- Kernel 1: norms + bf16 conversion ----------------
__global__ __launch_bounds__(256) void prep_kernel(
    const float* __restrict__ f, float* __restrict__ sq,
    unsigned short* __restrict__ fbf) {
  const int wid = threadIdx.x >> 6;
  const int lane = threadIdx.x & 63;
  const int row = blockIdx.x * 4 + wid;
  const float4* fr = (const float4*)(f + (size_t)row * DIM);
  ushort4* br = (ushort4*)(fbf + (size_t)row * DIM);
  float s = 0.f;
#pragma unroll
  for (int u = 0; u < 2; ++u) {
    float4 v = fr[u * 64 + lane];
    s += v.x * v.x + v.y * v.y + v.z * v.z + v.w * v.w;
    ushort4 h;
    h.x = f2bf(v.x); h.y = f2bf(v.y); h.z = f2bf(v.z); h.w = f2bf(v.w);
    br[u * 64 + lane] = h;
  }
#pragma unroll
  for (int off = 32; off; off >>= 1) s += __shfl_down(s, off);
  if (lane == 0) sq[row] = s;
}

// ---------------- Kernel 2: 64x64 tiles + underflow-skip epilogue -----------
// grid (192, 8). Round-10 structure (BK=64, gload_lds w/ source-side swizzle,
// double-buffer, stage-before-compute) + ONE new lever:
//
// UNDERFLOW-SKIP (provably output-equivalent for ANY input): after ct=0 each
// thread's top-10 list is full with sims >= 0.0 at the lowest indices of this
// chunk. A later tile in which EVERY dist >= 104 yields sim == +0.0f exactly
// (exp(-104) < half of FLT_MIN_SUBNORM), and a 0.0 at a higher index can
// never displace a (v desc, idx asc)-sorted list entry (v>=0, smaller idx).
// So the whole epilogue (expf, sim-LDS write, scan, 2 barriers) is a no-op;
// one __syncthreads_and vote (dist check = 3 VALU ops/elem on register data)
// replaces it. ct=0 always takes the full path. Round-10 counters said the
// epilogue was ~20-25% of CU cycles and most residual bank conflicts.
__global__ __launch_bounds__(256) void gram_topk(
    const unsigned short* __restrict__ fbf, const float* __restrict__ sq,
    float2* __restrict__ part, float* __restrict__ out) {
  // smem: staging buffers A0|A1|B0|B1 (4 x 8KB). simf [64][66] f32 (16896B)
  // and the merge dump (20480B) OVERLAY the buffers (dead at those points).
  __shared__ __align__(16) char smem[32768];
  __shared__ float sqrow[BT];
  float* simf = (float*)smem;

  const int t = threadIdx.x;
  const int lane = t & 63, wid = t >> 6;
  const int wr = wid >> 1, wc = wid & 1;      // wave -> 32x32 quadrant
  const int fr = lane & 15, kg = lane >> 4;   // MFMA fragment coords
  const int brow = blockIdx.x * BT;
  const int chunk = blockIdx.y;

  // Zero-fill this block's 1/1536 slice of the output.
  {
    const int bid = blockIdx.y * NRB + blockIdx.x;         // 0..1535
    const int per = NROWS * NROWS / (NRB * NC) / 4;        // f32x4 per block
    f32x4* o4 = (f32x4*)out + (size_t)bid * per;
    f32x4 z = {0.f, 0.f, 0.f, 0.f};
    for (int i = t; i < per; i += 256) o4[i] = z;
  }
  if (t < BT) sqrow[t] = sq[brow + t];

  float tv[10]; int ti[10];
#pragma unroll
  for (int s = 0; s < 10; ++s) { tv[s] = -INFINITY; ti[s] = 0x7fffffff; }

  // staging geometry: 512 chunks of 16B per matrix per k-step; thread t takes
  // chunks t and t+256. chunk c: row=c>>3, slot=c&7, src k-group = slot^(row&7).
  const int c0r = t >> 3;
  const int c1r = (t + 256) >> 3;
  const size_t g0 = (size_t)c0r * DIM + (((t & 7) ^ (c0r & 7)) * 8);
  const size_t g1 = (size_t)c1r * DIM + (((t & 7) ^ (c1r & 7)) * 8);
  const int d0 = wid * 1024;          // LDS dest base, wave-uniform (+lane*16 by HW)
  const int d1 = 4096 + wid * 1024;
  const unsigned short* arow = fbf + (size_t)brow * DIM;

  for (int ct = 0; ct < CT; ++ct) {
    const int bcol = chunk * CHUNK + ct * BT;
    const unsigned short* bcolp = fbf + (size_t)bcol * DIM;

    f32x4 acc[2][2];
#pragma unroll
    for (int m = 0; m < 2; ++m)
#pragma unroll
      for (int n = 0; n < 2; ++n)
#pragma unroll
        for (int q = 0; q < 4; ++q) acc[m][n][q] = 0.f;

    // stage(kt, buf): issue 4 global_load_lds (A x2, B x2)
#define STAGE(KT, BUF)                                                       \
    do {                                                                     \
      char* ab_ = smem + (BUF) * 8192;                                       \
      char* bb_ = smem + 16384 + (BUF) * 8192;                               \
      gload16(arow + (KT) + g0, ab_ + d0);                                   \
      gload16(arow + (KT) + g1, ab_ + d1);                                   \
      gload16(bcolp + (KT) + g0, bb_ + d0);                                  \
      gload16(bcolp + (KT) + g1, bb_ + d1);                                  \
    } while (0)

    STAGE(0, 0);
    __syncthreads();   // buf0 ready (vmcnt drained); also covers sqrow init

    for (int k = 0; k < KST; ++k) {
      if (k < KST - 1) STAGE((k + 1) * BK2, (k + 1) & 1);
      const char* ab = smem + (k & 1) * 8192;
      const char* bb = smem + 16384 + (k & 1) * 8192;
#pragma unroll
      for (int h = 0; h < 2; ++h) {
        const int ob = (((h << 2) | kg) ^ (fr & 7)) << 4;
        s16x8 a0 = *(const s16x8*)(ab + (wr * 32 + fr) * 128 + ob);
        s16x8 a1 = *(const s16x8*)(ab + (wr * 32 + 16 + fr) * 128 + ob);
        s16x8 b0 = *(const s16x8*)(bb + (wc * 32 + fr) * 128 + ob);
        s16x8 b1 = *(const s16x8*)(bb + (wc * 32 + 16 + fr) * 128 + ob);
        acc[0][0] = __builtin_amdgcn_mfma_f32_16x16x32_bf16(a0, b0, acc[0][0], 0, 0, 0);
        acc[0][1] = __builtin_amdgcn_mfma_f32_16x16x32_bf16(a0, b1, acc[0][1], 0, 0, 0);
        acc[1][0] = __builtin_amdgcn_mfma_f32_16x16x32_bf16(a1, b0, acc[1][0], 0, 0, 0);
        acc[1][1] = __builtin_amdgcn_mfma_f32_16x16x32_bf16(a1, b1, acc[1][1], 0, 0, 0);
      }
      __syncthreads();  // readers done with buf(k) + stage(k+1) drained
    }
#undef STAGE

    // Per-thread column norms (2 distinct cols per thread), register-hoisted.
    const float sqc0 = sq[bcol + wc * 32 + fr];
    const float sqc1 = sq[bcol + wc * 32 + 16 + fr];

    // Underflow vote: does ANY element of this tile have dist < 104?
    bool under = (ct > 0);
#pragma unroll
    for (int m = 0; m < 2; ++m)
#pragma unroll
      for (int n = 0; n < 2; ++n) {
        const float sqc = n ? sqc1 : sqc0;
#pragma unroll
        for (int q = 0; q < 4; ++q) {
          const int rl = wr * 32 + m * 16 + kg * 4 + q;
          const float dist = sqrow[rl] + sqc - 2.0f * acc[m][n][q];
          under = under && (dist >= UNDERFLOW_DIST);
        }
      }
    const int skip = __syncthreads_and((int)under);  // block-uniform

    if (!skip) {
      // Full epilogue: dist -> sim, LDS tile, stable scan.
      // C/D layout: col=lane&15, row=(lane>>4)*4+q. All acc indices static.
#pragma unroll
      for (int m = 0; m < 2; ++m)
#pragma unroll
        for (int n = 0; n < 2; ++n)
#pragma unroll
          for (int q = 0; q < 4; ++q) {
            int rl = wr * 32 + m * 16 + kg * 4 + q;
            int cl = wc * 32 + n * 16 + fr;
            float dist = sqrow[rl] + (n ? sqc1 : sqc0) - 2.0f * acc[m][n][q];
            float sv = ((brow + rl) == (bcol + cl)) ? 0.0f
                       : __expf(-fmaxf(dist, 0.0f));
            simf[rl * 66 + cl] = sv;
          }
      __syncthreads();

      // Scan: wave `wid` scans its 16-col sub-slice of each of the 64 rows.
      {
        const int c0 = wid * 16;
#pragma unroll
        for (int c = 0; c < 16; ++c) {
          float v = simf[lane * 66 + c0 + c];
          TOPK_INSERT(tv, ti, v, bcol + c0 + c);
        }
      }
      __syncthreads();   // scan done before buffers are re-staged next ct
    }
  }

  // Dump 4 partial lists per row to LDS, then one thread per row merges and
  // writes the row's chunk top-10 to the workspace.
#pragma unroll
  for (int s = 0; s < 10; ++s) {
    simf[(lane * 4 + wid) * 20 + s * 2]     = tv[s];
    simf[(lane * 4 + wid) * 20 + s * 2 + 1] = __int_as_float(ti[s]);
  }
  __syncthreads();
  if (t < BT) {
    float mv[10]; int mi[10];
#pragma unroll
    for (int s = 0; s < 10; ++s) { mv[s] = -INFINITY; mi[s] = 0x7fffffff; }
#pragma unroll
    for (int p = 0; p < 4; ++p)
#pragma unroll
      for (int s = 0; s < 10; ++s) {
        float v = simf[(t * 4 + p) * 20 + s * 2];
        int idx = __float_as_int(simf[(t * 4 + p) * 20 + s * 2 + 1]);
        TOPK_INSERT(mv, mi, v, idx);
      }
    float2* dst = part + ((size_t)(brow + t) * NC + chunk) * 10;
#pragma unroll
    for (int s = 0; s < 10; ++s) dst[s] = make_float2(mv[s], __int_as_float(mi[s]));
  }
}

// ---------------- Kernel 3: merge NC chunk lists per row, scatter ones ------
__global__ __launch_bounds__(256) void merge_scatter(
    const float2* __restrict__ part, float* __restrict__ out) {
  const int t = threadIdx.x;
  if (t >= 128) return;
  const int r = blockIdx.x * 128 + t;
  float mv[10]; int mi[10];
#pragma unroll
  for (int s = 0; s < 10; ++s) { mv[s] = -INFINITY; mi[s] = 0x7fffffff; }
  const float2* p = part + (size_t)r * NC * 10;
#pragma unroll
  for (int c = 0; c < NC * 10; ++c)
    TOPK_INSERT(mv, mi, p[c].x, __float_as_int(p[c].y));
  float* orow = out + (size_t)r * NROWS;
#pragma unroll
  for (int s = 0; s < 10; ++s) orow[mi[s]] = 1.0f;
}

// ---------------- Fallback (round-1 single-kernel path, 12.6 MB ws) ---------
__global__ __launch_bounds__(256) void knn_fallback(
    const unsigned short* __restrict__ fbf, const float* __restrict__ sq,
    float* __restrict__ out) {
  __shared__ short aT[64][32];
  __shared__ short bT[64][32];
  __shared__ float simf[5120];
  __shared__ float sqrow[64];

  const int t = threadIdx.x;
  const int lane = t & 63, wid = t >> 6;
  const int wr = wid >> 1, wc = wid & 1;
  const int fr = lane & 15, kg = lane >> 4;
  const int brow = blockIdx.x * 64;

  {
    f32x4* o4 = (f32x4*)(out + (size_t)brow * NROWS);
    const int total4 = 64 * NROWS / 4;
    f32x4 z = {0.f, 0.f, 0.f, 0.f};
    for (int i = t; i < total4; i += 256) o4[i] = z;
  }
  if (t < 64) sqrow[t] = sq[brow + t];

  float tv[10]; int ti[10];
#pragma unroll
  for (int s = 0; s < 10; ++s) { tv[s] = -INFINITY; ti[s] = 0x7fffffff; }
  const int sstage_r = t >> 2;
  const int sstage_k = (t & 3) * 8;

  for (int ctile = 0; ctile < NROWS / 64; ++ctile) {
    const int bcol = ctile * 64;
    f32x4 acc[2][2];
#pragma unroll
    for (int m = 0; m < 2; ++m)
#pragma unroll
      for (int n = 0; n < 2; ++n)
#pragma unroll
        for (int q = 0; q < 4; ++q) acc[m][n][q] = 0.f;

    for (int kt = 0; kt < DIM; kt += 32) {
      *(s16x8*)&aT[sstage_r][sstage_k] =
          *(const s16x8*)&fbf[(size_t)(brow + sstage_r) * DIM + kt + sstage_k];
      *(s16x8*)&bT[sstage_r][sstage_k] =
          *(const s16x8*)&fbf[(size_t)(bcol + sstage_r) * DIM + kt + sstage_k];
      __syncthreads();
      s16x8 a0 = *(const s16x8*)&aT[wr * 32 + fr][kg * 8];
      s16x8 a1 = *(const s16x8*)&aT[wr * 32 + 16 + fr][kg * 8];
      s16x8 b0 = *(const s16x8*)&bT[wc * 32 + fr][kg * 8];
      s16x8 b1 = *(const s16x8*)&bT[wc * 32 + 16 + fr][kg * 8];
      acc[0][0] = __builtin_amdgcn_mfma_f32_16x16x32_bf16(a0, b0, acc[0][0], 0, 0, 0);
      acc[0][1] = __builtin_amdgcn_mfma_f32_16x16x32_bf16(a0, b1, acc[0][1], 0, 0, 0);
      acc[1][0] = __builtin_amdgcn_mfma_f32_16x16x32_bf16(a1, b0, acc[1][0], 0, 0, 0);
      acc[1][1] = __builtin_amdgcn_mfma_f32_16x16x32_bf16(a1, b1, acc[1][1], 0, 0, 0);
      __syncthreads();
    }
#pragma unroll
    for (int m = 0; m < 2; ++m)
#pragma unroll
      for (int n = 0; n < 2; ++n)
#pragma unroll
        for (int q = 0; q < 4; ++q) {
          int rl = wr * 32 + m * 16 + kg * 4 + q;
          int cl = wc * 32 + n * 16 + fr;
          float dist = sqrow[rl] + sq[bcol + cl] - 2.0f * acc[m][n][q];
          float sv = ((brow + rl) == (bcol + cl)) ? 0.0f : __expf(-fmaxf(dist, 0.0f));
          simf[rl * 65 + cl] = sv;
        }
    __syncthreads();
    {
      const int c0 = wid * 16;
#pragma unroll
      for (int c = 0; c < 16; ++c) {
        float v = simf[lane * 65 + c0 + c];
        TOPK_INSERT(tv, ti, v, bcol + c0 + c);
      }
    }
    __syncthreads();
  }
#pragma unroll
  for (int s = 0; s < 10; ++s) {
    simf[(lane * 4 + wid) * 20 + s * 2]     = tv[s];
    simf[(lane * 4 + wid) * 20 + s * 2 + 1] = __int_as_float(ti[s]);
  }
  __syncthreads();
  if (t < 64) {
    float mv[10]; int mi[10];
#pragma unroll
    for (int s = 0; s < 10; ++s) { mv[s] = -INFINITY; mi[s] = 0x7fffffff; }
#pragma unroll
    for (int p = 0; p < 4; ++p)
#pragma unroll
      for (int s = 0; s < 10; ++s) {
        float v = simf[(t * 4 + p) * 20 + s * 2];
        int idx = __float_as_int(simf[(t * 4 + p) * 20 + s * 2 + 1]);
        TOPK_INSERT(mv, mi, v, idx);
      }
    float* orow = out + (size_t)(brow + t) * NROWS;
#pragma unroll
    for (int s = 0; s < 10; ++s) orow[mi[s]] = 1.0f;
  }
}

extern "C" void kernel_launch(void* const* d_in, const int* in_sizes, int n_in,
                              void* d_out, int out_size, void* d_ws, size_t ws_size,
                              hipStream_t stream) {
  const float* f = (const float*)d_in[0];
  float* out = (float*)d_out;

  const size_t sq_bytes   = (size_t)NROWS * sizeof(float);          // 49152
  const size_t fbf_bytes  = (size_t)NROWS * DIM * sizeof(unsigned short);
  const size_t part_bytes = (size_t)NROWS * NC * 10 * sizeof(float2);

  float* sq = (float*)d_ws;
  unsigned short* fbf = (unsigned short*)((char*)d_ws + sq_bytes);
  float2* part = (float2*)((char*)d_ws + sq_bytes + fbf_bytes);

  if (ws_size >= sq_bytes + fbf_bytes + part_bytes) {
    prep_kernel<<<NROWS / 4, 256, 0, stream>>>(f, sq, fbf);
    gram_topk<<<dim3(NRB, NC), 256, 0, stream>>>(fbf, sq, part, out);
    merge_scatter<<<NROWS / 128, 256, 0, stream>>>(part, out);
  } else if (ws_size >= sq_bytes + fbf_bytes) {
    prep_kernel<<<NROWS / 4, 256, 0, stream>>>(f, sq, fbf);
    knn_fallback<<<NROWS / 64, 256, 0, stream>>>(fbf, sq, out);
  }
}